// Round 5
// baseline (260.439 us; speedup 1.0000x reference)
//
#include <hip/hip_runtime.h>

// YOLOv1 loss: pre/lab [32768, 30, 7, 7] fp32 -> scalar (sum / B).
// Round 5: rounds 2-4 converged to 73-76 us (~87% of the 6.29 TB/s copy
// ceiling, combined HBM+L3 stream). Remaining overhead: the second launch.
// Fused single-kernel: last-block-done reduction via agent-scope atomics
// (cross-XCD-safe, deterministic fixed-order double sum). Counter zeroed
// per call with a 4-byte hipMemsetAsync (graph-capturable).

#define BATCH    32768
#define S2       49            // 7*7 cells per batch
#define CPB      1470          // floats per batch per tensor (30*49)
#define NB       2             // batches per group
#define GF       (NB * CPB)    // 2940 floats per group per tensor
#define GV       (GF / 4)      // 735 float4 per group per tensor
#define NGROUPS  (BATCH / NB)  // 16384
#define LDSB     492           // padded floats per batch in LDS (16B-aligned)
#define HALF     (NB * LDSB)   // 984: one tensor's LDS region (floats)
#define BUFSZ    (2 * HALF)    // 1968 floats per buffer (7872 B)
#define NBLK     2040
#define CELLBASE 158           // cells on threads 158..255 (lighter load tail)

__device__ __forceinline__ float iou4(float px1, float py1, float px2, float py2,
                                      float lx1, float ly1, float lx2, float ly2) {
    float ix1 = fmaxf(px1, lx1), iy1 = fmaxf(py1, ly1);
    float ix2 = fminf(px2, lx2), iy2 = fminf(py2, ly2);
    float iw = fmaxf(ix2 - ix1 + 1.0f, 0.0f);
    float ih = fmaxf(iy2 - iy1 + 1.0f, 0.0f);
    float inter = iw * ih;
    float a1 = (px2 - px1 + 1.0f) * (py2 - py1 + 1.0f);
    float a2 = (lx2 - lx1 + 1.0f) * (ly2 - ly1 + 1.0f);
    return inter / (a1 + a2 - inter);
}

// obj/noobj terms for one cell; P,L point at (batch-slot, s) inside LDS,
// channel stride 49 (<=2-way bank aliasing across a wave: free).
__device__ __forceinline__ float cell_loss(const float* P, const float* L) {
    float p0 = P[0],   p1 = P[49],  p2 = P[98],  p3 = P[147], p4 = P[196];
    float p5 = P[245], p6 = P[294], p7 = P[343], p8 = P[392], p9 = P[441];
    float l0 = L[0],   l1 = L[49],  l2 = L[98],  l3 = L[147], l4 = L[196];
    float l5 = L[245], l6 = L[294], l7 = L[343], l8 = L[392];

    float iou1 = iou4(p0, p1, p2, p3, l0, l1, l2, l3);
    float iou2 = iou4(p5, p6, p7, p8, l5, l6, l7, l8);
    bool resp1 = iou1 >= iou2;

    float d0 = l0 - p0, d1 = l1 - p1, d5 = l5 - p5, d6 = l6 - p6;
    float addr1 = 5.0f * (d0 * d0 + d1 * d1);
    float addr2 = 5.0f * (d5 * d5 + d6 * d6);

    float e2 = sqrtf(p2) - sqrtf(l2), e3 = sqrtf(p3) - sqrtf(l3);
    float e7 = sqrtf(p7) - sqrtf(l7), e8 = sqrtf(p8) - sqrtf(l8);
    float size1 = 5.0f * (e2 * e2 + e3 * e3);
    float size2 = 5.0f * (e7 * e7 + e8 * e8);

    float du = p9 - (resp1 ? iou1 : iou2);
    float conf = 0.5f * du * du;

    float obj_terms = (resp1 ? (addr1 + size1) : (addr2 + size2)) + conf;
    float pn = p4 + p9;
    float noobj = 0.5f * pn * pn;
    return (l4 == 1.0f) ? obj_terms : noobj;
}

// Route one float4 pair: coupled channels (local float idx < 490) -> LDS,
// cls -> squared-diff accumulate. No arrays anywhere (rule #20).
__device__ __forceinline__ void consume_one(float4 pv, float4 lv, int i,
                                            float* __restrict__ buf, float& acc) {
    int base = 4 * i;                 // group-local float index, 0..2936
    int bl = base >= CPB;
    int lo = base - bl * CPB;
    if (lo <= 486) {                  // all 4 coupled, same batch
        *(float4*)(buf + bl * LDSB + lo) = pv;
        *(float4*)(buf + HALF + bl * LDSB + lo) = lv;
    } else if (lo >= 490 && lo <= 1466) {   // all 4 cls
        float d0 = pv.x - lv.x, d1 = pv.y - lv.y;
        float d2 = pv.z - lv.z, d3 = pv.w - lv.w;
        acc += d0 * d0 + d1 * d1 + d2 * d2 + d3 * d3;
    } else if (lo == 488) {           // 488,489 coupled; 490,491 cls
        buf[bl * LDSB + 488] = pv.x;
        buf[bl * LDSB + 489] = pv.y;
        buf[HALF + bl * LDSB + 488] = lv.x;
        buf[HALF + bl * LDSB + 489] = lv.y;
        float d2 = pv.z - lv.z, d3 = pv.w - lv.w;
        acc += d2 * d2 + d3 * d3;
    } else {                          // lo == 1468: 1468,1469 cls; batch1 floats 0,1
        float d0 = pv.x - lv.x, d1 = pv.y - lv.y;
        acc += d0 * d0 + d1 * d1;
        buf[LDSB + 0] = pv.z;
        buf[LDSB + 1] = pv.w;
        buf[HALF + LDSB + 0] = lv.z;
        buf[HALF + LDSB + 1] = lv.w;
    }
}

__global__ __launch_bounds__(256) void yolo_loss_main(const float4* __restrict__ pre4,
                                                      const float4* __restrict__ lab4,
                                                      float* __restrict__ partials,
                                                      unsigned int* __restrict__ ctr,
                                                      int nblk,
                                                      float* __restrict__ out) {
    __shared__ __align__(16) float sbuf[2 * BUFSZ];
    __shared__ float red[4];
    __shared__ int lastflag;
    const int tid = threadIdx.x;
    const bool t2 = tid + 512 < GV;    // third load lane active (tid < 223)
    float acc = 0.0f;

    float* cb   = sbuf;                // compute buffer
    float* nbuf = sbuf + BUFSZ;        // staging target

    int g = blockIdx.x;
    if (g < NGROUPS) {
        {   // prologue: stage group g into cb
            const float4* __restrict__ ps = pre4 + (size_t)g * GV;
            const float4* __restrict__ ls = lab4 + (size_t)g * GV;
            float4 pa = ps[tid];
            float4 la = ls[tid];
            float4 pb = ps[tid + 256];
            float4 lb = ls[tid + 256];
            float4 pc, lc;
            if (t2) { pc = ps[tid + 512]; lc = ls[tid + 512]; }
            consume_one(pa, la, tid,       cb, acc);
            consume_one(pb, lb, tid + 256, cb, acc);
            if (t2) consume_one(pc, lc, tid + 512, cb, acc);
        }
        __syncthreads();

        for (;;) {
            int gn = g + gridDim.x;
            bool hn = gn < NGROUPS;
            float4 pa, la, pb, lb, pc, lc;
            if (hn) {   // issue loads for group t+1 first; latency hides under cells
                const float4* __restrict__ ps = pre4 + (size_t)gn * GV;
                const float4* __restrict__ ls = lab4 + (size_t)gn * GV;
                pa = ps[tid];
                la = ls[tid];
                pb = ps[tid + 256];
                lb = ls[tid + 256];
                if (t2) { pc = ps[tid + 512]; lc = ls[tid + 512]; }
            }
            // compute cells of group t from cb (threads 158..255)
            if (tid >= CELLBASE) {
                int ctid = tid - CELLBASE;
                int bl = ctid / S2, s = ctid - bl * S2;
                acc += cell_loss(cb + bl * LDSB + s, cb + HALF + bl * LDSB + s);
            }
            // consume in issue order -> progressive vmcnt
            if (hn) {
                consume_one(pa, la, tid,       nbuf, acc);
                consume_one(pb, lb, tid + 256, nbuf, acc);
                if (t2) consume_one(pc, lc, tid + 512, nbuf, acc);
            }
            __syncthreads();
            if (!hn) break;
            g = gn;
            float* t = cb; cb = nbuf; nbuf = t;
        }
    }

    // block reduction (deterministic): wave butterfly, then 4 fixed adds
    #pragma unroll
    for (int off = 32; off > 0; off >>= 1) acc += __shfl_down(acc, off);
    int lane = tid & 63, wid = tid >> 6;
    if (lane == 0) red[wid] = acc;
    __syncthreads();
    if (tid == 0) {
        float bs = red[0] + red[1] + red[2] + red[3];
        // agent-scope store: visible across non-coherent per-XCD L2s
        __hip_atomic_store(&partials[blockIdx.x], bs, __ATOMIC_RELEASE,
                           __HIP_MEMORY_SCOPE_AGENT);
        unsigned prev = __hip_atomic_fetch_add(ctr, 1u, __ATOMIC_ACQ_REL,
                                               __HIP_MEMORY_SCOPE_AGENT);
        lastflag = (prev == (unsigned)(nblk - 1)) ? 1 : 0;
    }
    __syncthreads();

    if (lastflag) {   // block-uniform: only the last-finishing block enters
        double v = 0.0;
        for (int i = tid; i < nblk; i += 256)
            v += (double)__hip_atomic_load(&partials[i], __ATOMIC_RELAXED,
                                           __HIP_MEMORY_SCOPE_AGENT);
        #pragma unroll
        for (int off = 32; off > 0; off >>= 1) v += __shfl_down(v, off);
        __shared__ double dred[4];
        if ((tid & 63) == 0) dred[tid >> 6] = v;
        __syncthreads();
        if (tid == 0)
            out[0] = (float)((dred[0] + dred[1] + dred[2] + dred[3]) * (1.0 / 32768.0));
    }
}

extern "C" void kernel_launch(void* const* d_in, const int* in_sizes, int n_in,
                              void* d_out, int out_size, void* d_ws, size_t ws_size,
                              hipStream_t stream) {
    const float4* pre4 = (const float4*)d_in[0];
    const float4* lab4 = (const float4*)d_in[1];
    float* out = (float*)d_out;
    unsigned int* ctr = (unsigned int*)d_ws;           // [0]: arrival counter
    float* partials = (float*)d_ws + 1;                // [1..nblk]

    int nblk = NBLK;
    size_t need = (size_t)(nblk + 1) * sizeof(float);
    if (ws_size < need) {
        nblk = (int)(ws_size / sizeof(float)) - 1;
        if (nblk < 1) nblk = 1;
    }

    hipMemsetAsync(d_ws, 0, sizeof(unsigned int), stream);   // zero counter each call
    yolo_loss_main<<<nblk, 256, 0, stream>>>(pre4, lab4, partials, ctr, nblk, out);
}

// Round 6
// 74.164 us; speedup vs baseline: 3.5117x; 3.5117x over previous
//
#include <hip/hip_runtime.h>

// YOLOv1 loss: pre/lab [32768, 30, 7, 7] fp32 -> scalar (sum / B).
// Round 6: REVERT round-5 fusion (agent-scope acq_rel atomics per block force
// per-XCD L2 writeback/invalidate -> 4x slowdown). Back to the proven
// two-kernel stream (best measured: 73.0 us), plus:
//  - cls channels (10..29) squared-diff'd in registers during consume (no LDS)
//  - lab float4s fully inside lab channel 9 (never read) are not loaded
//    (23/1470 vectors per group, -1.5% bytes)
// Single LDS buffer, 2 barriers/group; latency is irrelevant at ~21k cycles
// per group (proven by R2=73.0 with full serialization).

#define BATCH   32768
#define S2      49            // 7*7 cells per batch
#define CPB     1470          // floats per batch per tensor (30*49)
#define NB      2             // batches per group
#define GF      (NB * CPB)    // 2940 floats per group per tensor
#define GV      (GF / 4)      // 735 float4 per group per tensor
#define NGROUPS (BATCH / NB)  // 16384
#define LDSB    492           // padded floats per batch in LDS (16B-aligned)
#define HALF    (NB * LDSB)   // 984: one tensor's LDS region (floats)
#define BUFSZ   (2 * HALF)    // 1968 floats (7872 B), single buffer
#define NBLK    2048

__device__ __forceinline__ float iou4(float px1, float py1, float px2, float py2,
                                      float lx1, float ly1, float lx2, float ly2) {
    float ix1 = fmaxf(px1, lx1), iy1 = fmaxf(py1, ly1);
    float ix2 = fminf(px2, lx2), iy2 = fminf(py2, ly2);
    float iw = fmaxf(ix2 - ix1 + 1.0f, 0.0f);
    float ih = fmaxf(iy2 - iy1 + 1.0f, 0.0f);
    float inter = iw * ih;
    float a1 = (px2 - px1 + 1.0f) * (py2 - py1 + 1.0f);
    float a2 = (lx2 - lx1 + 1.0f) * (ly2 - ly1 + 1.0f);
    return inter / (a1 + a2 - inter);
}

// obj/noobj terms for one cell; P,L point at (batch-slot, s) inside LDS,
// channel stride 49 (<=2-way bank aliasing across a wave: free).
__device__ __forceinline__ float cell_loss(const float* P, const float* L) {
    float p0 = P[0],   p1 = P[49],  p2 = P[98],  p3 = P[147], p4 = P[196];
    float p5 = P[245], p6 = P[294], p7 = P[343], p8 = P[392], p9 = P[441];
    float l0 = L[0],   l1 = L[49],  l2 = L[98],  l3 = L[147], l4 = L[196];
    float l5 = L[245], l6 = L[294], l7 = L[343], l8 = L[392];

    float iou1 = iou4(p0, p1, p2, p3, l0, l1, l2, l3);
    float iou2 = iou4(p5, p6, p7, p8, l5, l6, l7, l8);
    bool resp1 = iou1 >= iou2;

    float d0 = l0 - p0, d1 = l1 - p1, d5 = l5 - p5, d6 = l6 - p6;
    float addr1 = 5.0f * (d0 * d0 + d1 * d1);
    float addr2 = 5.0f * (d5 * d5 + d6 * d6);

    float e2 = sqrtf(p2) - sqrtf(l2), e3 = sqrtf(p3) - sqrtf(l3);
    float e7 = sqrtf(p7) - sqrtf(l7), e8 = sqrtf(p8) - sqrtf(l8);
    float size1 = 5.0f * (e2 * e2 + e3 * e3);
    float size2 = 5.0f * (e7 * e7 + e8 * e8);

    float du = p9 - (resp1 ? iou1 : iou2);
    float conf = 0.5f * du * du;

    float obj_terms = (resp1 ? (addr1 + size1) : (addr2 + size2)) + conf;
    float pn = p4 + p9;
    float noobj = 0.5f * pn * pn;
    return (l4 == 1.0f) ? obj_terms : noobj;
}

// Route one float4 pair. lab_ok==false means the lab vector lies fully inside
// lab channel 9 (floats 441..489 of its batch): lv was not loaded and is
// neither written to LDS nor read by cell_loss.
__device__ __forceinline__ void consume_pair(float4 pv, float4 lv, int i,
                                             bool lab_ok,
                                             float* __restrict__ buf, float& acc) {
    int base = 4 * i;                 // group-local float index, 0..2936
    int bl = base >= CPB;
    int lo = base - bl * CPB;
    if (lo <= 486) {                  // all 4 coupled, same batch
        *(float4*)(buf + bl * LDSB + lo) = pv;
        if (lab_ok)
            *(float4*)(buf + HALF + bl * LDSB + lo) = lv;
    } else if (lo >= 490 && lo <= 1466) {   // all 4 cls
        float d0 = pv.x - lv.x, d1 = pv.y - lv.y;
        float d2 = pv.z - lv.z, d3 = pv.w - lv.w;
        acc += d0 * d0 + d1 * d1 + d2 * d2 + d3 * d3;
    } else if (lo == 488) {           // 488,489 coupled (ch9, unread); 490,491 cls
        buf[bl * LDSB + 488] = pv.x;
        buf[bl * LDSB + 489] = pv.y;
        float d2 = pv.z - lv.z, d3 = pv.w - lv.w;
        acc += d2 * d2 + d3 * d3;
    } else {                          // lo == 1468: 1468,1469 cls; batch1 floats 0,1
        float d0 = pv.x - lv.x, d1 = pv.y - lv.y;
        acc += d0 * d0 + d1 * d1;
        buf[LDSB + 0] = pv.z;
        buf[LDSB + 1] = pv.w;
        buf[HALF + LDSB + 0] = lv.z;
        buf[HALF + LDSB + 1] = lv.w;
    }
}

// Is lab float4 #i (group-local) fully inside lab channel 9 of its batch?
__device__ __forceinline__ bool lab_needed(int i) {
    int base = 4 * i;
    int bl = base >= CPB;
    int lo = base - bl * CPB;
    return !(lo >= 441 && lo <= 486);
}

__global__ __launch_bounds__(256) void yolo_loss_main(const float4* __restrict__ pre4,
                                                      const float4* __restrict__ lab4,
                                                      float* __restrict__ partials) {
    __shared__ __align__(16) float sbuf[BUFSZ];
    __shared__ float red[4];
    const int tid = threadIdx.x;
    const int i0 = tid, i1 = tid + 256, i2 = tid + 512;
    const bool t2 = i2 < GV;                  // third vector active (tid < 223)
    const bool nl0 = lab_needed(i0);
    const bool nl1 = lab_needed(i1);
    const bool nl2 = t2 ? lab_needed(i2) : false;
    float acc = 0.0f;

    for (int g = blockIdx.x; g < NGROUPS; g += gridDim.x) {
        const float4* __restrict__ ps = pre4 + (size_t)g * GV;
        const float4* __restrict__ ls = lab4 + (size_t)g * GV;
        float4 pa = ps[i0];
        float4 pb = ps[i1];
        float4 pc;
        if (t2) pc = ps[i2];
        float4 la, lb, lc;
        if (nl0) la = ls[i0];
        if (nl1) lb = ls[i1];
        if (nl2) lc = ls[i2];

        consume_pair(pa, la, i0, nl0, sbuf, acc);
        consume_pair(pb, lb, i1, nl1, sbuf, acc);
        if (t2) consume_pair(pc, lc, i2, nl2, sbuf, acc);
        __syncthreads();

        if (tid < NB * S2) {
            int bl = tid / S2, s = tid - bl * S2;
            acc += cell_loss(sbuf + bl * LDSB + s, sbuf + HALF + bl * LDSB + s);
        }
        __syncthreads();
    }

    // wave butterfly reduce, then cross-wave via LDS (deterministic)
    #pragma unroll
    for (int off = 32; off > 0; off >>= 1) acc += __shfl_down(acc, off);
    int lane = tid & 63, wid = tid >> 6;
    if (lane == 0) red[wid] = acc;
    __syncthreads();
    if (tid == 0) partials[blockIdx.x] = red[0] + red[1] + red[2] + red[3];
}

__global__ __launch_bounds__(256) void yolo_loss_final(const float* __restrict__ partials,
                                                       int n, float* __restrict__ out) {
    double v = 0.0;
    for (int i = (int)threadIdx.x; i < n; i += 256) v += (double)partials[i];
    __shared__ double sm[256];
    sm[threadIdx.x] = v;
    __syncthreads();
    for (int s = 128; s > 0; s >>= 1) {
        if ((int)threadIdx.x < s) sm[threadIdx.x] += sm[threadIdx.x + s];
        __syncthreads();
    }
    if (threadIdx.x == 0) out[0] = (float)(sm[0] * (1.0 / 32768.0));
}

extern "C" void kernel_launch(void* const* d_in, const int* in_sizes, int n_in,
                              void* d_out, int out_size, void* d_ws, size_t ws_size,
                              hipStream_t stream) {
    const float4* pre4 = (const float4*)d_in[0];
    const float4* lab4 = (const float4*)d_in[1];
    float* out = (float*)d_out;
    float* partials = (float*)d_ws;

    int nblk = NBLK;
    if (ws_size < (size_t)nblk * sizeof(float)) {
        nblk = (int)(ws_size / sizeof(float));
        if (nblk < 1) nblk = 1;
    }

    yolo_loss_main<<<nblk, 256, 0, stream>>>(pre4, lab4, partials);
    yolo_loss_final<<<1, 256, 0, stream>>>(partials, nblk, out);
}